// Round 18
// baseline (222.221 us; speedup 1.0000x reference)
//
#include <hip/hip_runtime.h>
#include <hip/hip_bf16.h>

typedef __attribute__((ext_vector_type(8))) short short8;
typedef __attribute__((ext_vector_type(4))) short short4v;
typedef __attribute__((ext_vector_type(4))) float f32x4;
typedef unsigned short us;

#define MFMA16(a,b,c) __builtin_amdgcn_mfma_f32_16x16x32_bf16((a),(b),(c),0,0,0)
#define LOG2E 1.4426950408889634f

static __device__ __forceinline__ us bf16r(float x){
  unsigned u = __builtin_bit_cast(unsigned, x);
  u = u + 0x7fffu + ((u >> 16) & 1u);
  return (us)(u >> 16);
}
static __device__ __forceinline__ unsigned cvtpk(float a, float b){
  unsigned r; asm("v_cvt_pk_bf16_f32 %0, %1, %2" : "=v"(r) : "v"(a), "v"(b)); return r;
}
static __device__ __forceinline__ float b2f(us h){
  return __builtin_bit_cast(float, (unsigned)h << 16);
}
static __device__ __forceinline__ float PKLO(unsigned u){
  return __builtin_bit_cast(float, u << 16);
}
static __device__ __forceinline__ float PKHI(unsigned u){
  return __builtin_bit_cast(float, u & 0xffff0000u);
}
static __device__ __forceinline__ float exp2fast(float x){
  float r; asm("v_exp_f32 %0, %1" : "=v"(r) : "v"(x)); return r;
}
static __device__ __forceinline__ float rcpfast(float x){
  float r; asm("v_rcp_f32 %0, %1" : "=v"(r) : "v"(x)); return r;
}
static __device__ __forceinline__ float fractfast(float x){
  float r; asm("v_fract_f32 %0, %1" : "=v"(r) : "v"(x)); return r;
}
template<int CTRL, int RMASK>
static __device__ __forceinline__ float dpp_add(float x){
  int t = __builtin_amdgcn_update_dpp(0, __builtin_bit_cast(int, x), CTRL, RMASK, 0xf, false);
  return x + __builtin_bit_cast(float, t);
}
static __device__ __forceinline__ float wave_iscan(float x){
  x = dpp_add<0x111, 0xf>(x);
  x = dpp_add<0x112, 0xf>(x);
  x = dpp_add<0x114, 0xf>(x);
  x = dpp_add<0x118, 0xf>(x);
  x = dpp_add<0x142, 0xa>(x);
  x = dpp_add<0x143, 0xc>(x);
  return x;
}
static __device__ __forceinline__ float lane63(float x){
  return __builtin_bit_cast(float, __builtin_amdgcn_readlane(__builtin_bit_cast(int, x), 63));
}
// global -> LDS direct (16B/lane). LDS dest = wave-uniform base + lane*16.
typedef const __attribute__((address_space(1))) unsigned cglb_u32;
typedef __attribute__((address_space(3))) unsigned lds_u32;
static __device__ __forceinline__ void gload16(const us* g, us* l){
  __builtin_amdgcn_global_load_lds((cglb_u32*)g, (lds_u32*)l, 16, 0, 0);
}

// ---------------- fp32 -> bf16 cast ----------------
__global__ __launch_bounds__(256)
void castf2b(const float* __restrict__ in, us* __restrict__ out, int n){
  const int i = (blockIdx.x * 256 + threadIdx.x) * 4;
  if (i < n){
    const float4 v = *(const float4*)(in + i);
    short4v o;
    o[0] = (short)bf16r(v.x); o[1] = (short)bf16r(v.y);
    o[2] = (short)bf16r(v.z); o[3] = (short)bf16r(v.w);
    *(short4v*)(out + i) = o;
  }
}

// ---------------- pos_emb [64d][64n] fp32 -> peT [64n][64d] bf16, pre-scaled by log2(e) ----
__global__ __launch_bounds__(256)
void transpose_pe(const float* __restrict__ pe, us* __restrict__ peT){
  const int t = threadIdx.x;
  const int n = t & 63, dq = t >> 6;
#pragma unroll
  for (int j = 0; j < 16; ++j){
    const int d = dq * 16 + j;
    peT[n * 64 + d] = bf16r(pe[d * 64 + n] * LOG2E);
  }
}

// ---------------- bf16 GEMM, global_load_lds staging (m97-class) ----------------
// C[4096][1024] = A[4096][1024] @ W[1024][1024]^T + bias. 128x128 tile, BK=64.
// Linear LDS dest + pre-swizzled global source; XOR-swizzled ds_read (rule #21).
// XCD swizzle: bm in [4x,4x+4) x all bn per XCD -> A 1MB + W 2MB < 4MB L2.
// sel==2 with VTo: write V transposed [b][h][64d][1024s] (fused transpose_v).
template<bool OUT_BF16>
__global__ __launch_bounds__(256)
void gemm_glds(const us* __restrict__ A0, const us* __restrict__ A1, const us* __restrict__ A2,
               const us* __restrict__ W0, const us* __restrict__ W1, const us* __restrict__ W2,
               const float* __restrict__ bp0, const float* __restrict__ bp1, const float* __restrict__ bp2,
               void* __restrict__ O0, void* __restrict__ O1, void* __restrict__ O2,
               us* __restrict__ VTo){
  __shared__ __align__(16) us Al[128 * 64];
  __shared__ __align__(16) us Bl[128 * 64];
  const int sel = blockIdx.y;
  const us* A      = sel == 0 ? A0 : (sel == 1 ? A1 : A2);
  const us* Wm     = sel == 0 ? W0 : (sel == 1 ? W1 : W2);
  const float* bias = sel == 0 ? bp0 : (sel == 1 ? bp1 : bp2);
  void* Ov         = sel == 0 ? O0 : (sel == 1 ? O1 : O2);
  const int tid = threadIdx.x;
  const int wg = ((blockIdx.x & 7) << 5) | (blockIdx.x >> 3);   // XCD swizzle (256=8*32)
  const int bm = wg >> 3, bn = wg & 7;
  const int m0 = bm << 7, n0 = bn << 7;
  const int w = tid >> 6, l = tid & 63;
  const int lr = l & 15, lg = l >> 4;
  const int wm = (w & 1) << 6, wn = (w >> 1) << 6;
  // staging addresses: slot (w*4+c)*512 + l*8 elems; LDS linear, global pre-swizzled
  int grow[4], gcol[4], lbase[4];
#pragma unroll
  for (int c = 0; c < 4; ++c){
    const int slot = (w * 4 + c) * 512 + l * 8;
    const int row = slot >> 6;
    const int cgsw = (slot >> 3) & 7;
    const int cg = cgsw ^ (row & 7);
    grow[c] = row; gcol[c] = cg << 3; lbase[c] = (w * 4 + c) * 512;
  }
  const int swz = (lr & 7) << 3;
  f32x4 acc[4][4];
#pragma unroll
  for (int i = 0; i < 4; ++i)
#pragma unroll
    for (int j = 0; j < 4; ++j) acc[i][j] = (f32x4){0.f, 0.f, 0.f, 0.f};

  for (int k0 = 0; k0 < 1024; k0 += 64){
    __syncthreads();   // prior reads done
#pragma unroll
    for (int c = 0; c < 4; ++c){
      gload16(A  + (size_t)(m0 + grow[c]) * 1024 + k0 + gcol[c], Al + lbase[c]);
      gload16(Wm + (size_t)(n0 + grow[c]) * 1024 + k0 + gcol[c], Bl + lbase[c]);
    }
    __syncthreads();   // vmcnt drain: tiles resident
#pragma unroll
    for (int ks = 0; ks < 2; ++ks){
      short8 af[4], bfv[4];
#pragma unroll
      for (int mt = 0; mt < 4; ++mt)
        af[mt] = *(const short8*)&Al[(wm + mt * 16 + lr) * 64 + (((ks << 5) + (lg << 3)) ^ swz)];
#pragma unroll
      for (int nt = 0; nt < 4; ++nt)
        bfv[nt] = *(const short8*)&Bl[(wn + nt * 16 + lr) * 64 + (((ks << 5) + (lg << 3)) ^ swz)];
#pragma unroll
      for (int mt = 0; mt < 4; ++mt)
#pragma unroll
        for (int nt = 0; nt < 4; ++nt)
          acc[mt][nt] = MFMA16(af[mt], bfv[nt], acc[mt][nt]);
    }
  }
  float bb[4];
#pragma unroll
  for (int nt = 0; nt < 4; ++nt) bb[nt] = bias[n0 + wn + nt * 16 + lr];
  if (VTo != nullptr && sel == 2){
    // fused V-transpose epilogue
#pragma unroll
    for (int mt = 0; mt < 4; ++mt)
#pragma unroll
      for (int nt = 0; nt < 4; ++nt){
        const int n = n0 + wn + nt * 16 + lr;
        const int hh = n >> 6, dd = n & 63;
        const int mS = m0 + wm + mt * 16 + lg * 4;
        const int bb2 = mS >> 10, ss = mS & 1023;
        uint2 pk;
        pk.x = cvtpk(acc[mt][nt][0] + bb[nt], acc[mt][nt][1] + bb[nt]);
        pk.y = cvtpk(acc[mt][nt][2] + bb[nt], acc[mt][nt][3] + bb[nt]);
        *(uint2*)&VTo[((size_t)((bb2 * 16 + hh) * 64 + dd)) * 1024 + ss] = pk;
      }
    return;
  }
#pragma unroll
  for (int mt = 0; mt < 4; ++mt)
#pragma unroll
    for (int nt = 0; nt < 4; ++nt)
#pragma unroll
      for (int r = 0; r < 4; ++r){
        const size_t m = m0 + wm + mt * 16 + lg * 4 + r;
        const size_t n = n0 + wn + nt * 16 + lr;
        const float vv = acc[mt][nt][r] + bb[nt];
        if (OUT_BF16) ((us*)Ov)[m * 1024 + n] = bf16r(vv);
        else          ((float*)Ov)[m * 1024 + n] = vv;
      }
}

// ---------------- fused CoPE attention v15 (unchanged, best known: ~136 us) ------
__global__ __launch_bounds__(256, 4)
void cope_attn_v15(const us* __restrict__ Qb, const us* __restrict__ Kb,
                   const us* __restrict__ VT, const us* __restrict__ peT,
                   us* __restrict__ Ob){
  __shared__ __align__(16) unsigned uls[8 * 512];   // 16 KB transit/P union
  __shared__ float sums[16];
  us* yl16 = (us*)uls;
  char* ybytes = (char*)uls;
  const int tid = threadIdx.x;
  const int w = tid >> 6, l = tid & 63;
  const int lr = l & 15, lg = l >> 4;
  const int wg = ((blockIdx.x & 7) << 9) | (blockIdx.x >> 3);  // XCD swizzle
  const int qt = wg & 63;
  const int bh = wg >> 6;
  const int b = bh >> 4, h = bh & 15;
  const int q0 = qt << 4;
  const us* Qh = Qb + ((size_t)(b * 1024 + q0)) * 1024 + h * 64;
  const us* Kh = Kb + ((size_t)(b * 1024)) * 1024 + h * 64;
  const us* Vh = VT + ((size_t)bh) * 64 * 1024;
  const float QSC = 0.125f * LOG2E;
  const f32x4 zf = (f32x4){0.f, 0.f, 0.f, 0.f};

  const short8 aq0 = *(const short8*)(Qh + (size_t)lr * 1024 + lg * 8);
  const short8 aq1 = *(const short8*)(Qh + (size_t)lr * 1024 + 32 + lg * 8);

  // 1) li[q][n] = (Q . pos_emb)*log2e
  {
    f32x4 a = zf;
    const short8 p0 = *(const short8*)(peT + (size_t)(w * 16 + lr) * 64 + lg * 8);
    const short8 p1 = *(const short8*)(peT + (size_t)(w * 16 + lr) * 64 + 32 + lg * 8);
    a = MFMA16(aq0, p0, a);
    a = MFMA16(aq1, p1, a);
#pragma unroll
    for (int r = 0; r < 4; ++r) yl16[(lg * 4 + r) * 64 + w * 16 + lr] = bf16r(a[r]);
  }
  __syncthreads();
  // 2) per-row register tables: lane n holds {li[n], li[n+1]-li[n]}
  unsigned trow[4];
#pragma unroll
  for (int rr = 0; rr < 4; ++rr){
    const int row = w * 4 + rr;
    const us lov = yl16[row * 64 + l];
    const us hiv = (l < 63) ? yl16[row * 64 + l + 1] : lov;
    const float dif = b2f(hiv) - b2f(lov);
    trow[rr] = (unsigned)lov | ((unsigned)bf16r(dif) << 16);
  }

  float carry[4] = {0.f, 0.f, 0.f, 0.f};
  f32x4 oacc = (f32x4){0.f, 0.f, 0.f, 0.f};
  const int d0 = w * 16;
  const int psw = lr & 7;

  for (int c = 1; c >= 0; --c){
    const int koff = c << 9;
    __syncthreads();
    // 3) QK^T -> packed u32 transit [pair][k]; wave keys [128w,128w+128)
    {
      const int kbase = w << 7;
      const us* Kw = Kh + (size_t)(koff + kbase + lr) * 1024 + lg * 8;
      for (int t = 0; t < 8; ++t){
        const short8 b0 = *(const short8*)(Kw + (size_t)(t * 16) * 1024);
        const short8 b1 = *(const short8*)(Kw + (size_t)(t * 16) * 1024 + 32);
        f32x4 a = zf;
        a = MFMA16(aq0, b0, a);
        a = MFMA16(aq1, b1, a);
        const int kc = kbase + t * 16 + lr;
        uls[(lg * 2) * 512 + kc]     = cvtpk(a[0] * QSC, a[1] * QSC);
        uls[(lg * 2 + 1) * 512 + kc] = cvtpk(a[2] * QSC, a[3] * QSC);
      }
    }
    __syncthreads();
    // 4) CoPE: wave owns pairs {2w,2w+1} = q rows 4w..4w+3; lane owns k [8l,8l+8)
#pragma unroll
    for (int pp = 0; pp < 2; ++pp){
      const int pr = w * 2 + pp;
      const uint4 ra = *(const uint4*)&uls[pr * 512 + l * 8];
      const uint4 rb = *(const uint4*)&uls[pr * 512 + l * 8 + 4];
#pragma unroll
      for (int par = 0; par < 2; ++par){
        const int rr = pp * 2 + par;
        const int row = w * 4 + rr;
        float x[8];
        if (par == 0){
          x[0] = PKLO(ra.x); x[1] = PKLO(ra.y); x[2] = PKLO(ra.z); x[3] = PKLO(ra.w);
          x[4] = PKLO(rb.x); x[5] = PKLO(rb.y); x[6] = PKLO(rb.z); x[7] = PKLO(rb.w);
        } else {
          x[0] = PKHI(ra.x); x[1] = PKHI(ra.y); x[2] = PKHI(ra.z); x[3] = PKHI(ra.w);
          x[4] = PKHI(rb.x); x[5] = PKHI(rb.y); x[6] = PKHI(rb.z); x[7] = PKHI(rb.w);
        }
        float sum = 0.f;
        if (c == 0 && carry[rr] >= 63.f){
          const float li63 = b2f((us)(unsigned)__builtin_amdgcn_readlane((int)trow[rr], 63));
#pragma unroll
          for (int i = 0; i < 8; ++i){
            const float e = exp2fast(x[i] + li63);
            x[i] = e;
            sum += e;
          }
        } else {
          float g[8];
#pragma unroll
          for (int i = 0; i < 8; ++i) g[i] = rcpfast(1.f + exp2fast(-x[i]));
          const float a1 = g[0] + g[1];
          const float a3 = g[2] + g[3];
          const float a5 = g[4] + g[5];
          const float a7 = g[6] + g[7];
          const float b2v = g[2] + a1;
          const float b3v = a3 + a1;
          const float i4 = g[4] + b3v;
          const float i5 = a5 + b3v;
          const float i6 = g[6] + a5 + b3v;
          const float s  = a7 + a5 + b3v;
          float pref[8];
          pref[0] = 0.f;  pref[1] = g[0]; pref[2] = a1;  pref[3] = b2v;
          pref[4] = b3v;  pref[5] = i4;   pref[6] = i5;  pref[7] = i6;
          const float run = wave_iscan(s);
          const float T = lane63(run);
          const float base = carry[rr] + T - (run - s);
          carry[rr] += T;
          const unsigned tbl = trow[rr];
#pragma unroll
          for (int i = 0; i < 8; ++i){
            float p = base - pref[i];
            p = __builtin_amdgcn_fmed3f(p, 0.f, 63.f);
            const int il = (int)p;
            const float wt = fractfast(p);
            const unsigned pr2 = (unsigned)__builtin_amdgcn_ds_bpermute(il << 2, (int)tbl);
            const float lo  = __builtin_bit_cast(float, pr2 << 16);
            const float dif = __builtin_bit_cast(float, pr2 & 0xffff0000u);
            const float e = exp2fast(x[i] + lo + wt * dif);
            x[i] = e;
            sum += e;
          }
        }
        const float rs = lane63(wave_iscan(sum));
        if (l == 0){
          if (c == 1) sums[row] = rs;
          else        sums[row] += rs;
        }
        uint4 ua;
        ua.x = cvtpk(x[0], x[1]); ua.y = cvtpk(x[2], x[3]);
        ua.z = cvtpk(x[4], x[5]); ua.w = cvtpk(x[6], x[7]);
        *(uint4*)(ybytes + row * 1024 + ((l ^ (row & 7)) << 4)) = ua;
      }
    }
    __syncthreads();
    // 5) PV accumulate: wave w owns d-tile [16w,16w+16)
    {
      const us* Vw = Vh + (size_t)(d0 + lr) * 1024 + koff + lg * 8;
      for (int ks = 0; ks < 16; ++ks){
        const short8 vb = *(const short8*)(Vw + ks * 32);
        const short8 pa = *(const short8*)(ybytes + lr * 1024 + ((((ks << 2) + lg) ^ psw) << 4));
        oacc = MFMA16(pa, vb, oacc);
      }
    }
  }
  __syncthreads();
#pragma unroll
  for (int r = 0; r < 4; ++r){
    const float inv = rcpfast(sums[lg * 4 + r]);
    Ob[((size_t)(b * 1024 + q0 + lg * 4 + r)) * 1024 + h * 64 + d0 + lr] = bf16r(oacc[r] * inv);
  }
}

extern "C" void kernel_launch(void* const* d_in, const int* in_sizes, int n_in,
                              void* d_out, int out_size, void* d_ws, size_t ws_size,
                              hipStream_t stream) {
  const float* q    = (const float*)d_in[0];
  const float* k    = (const float*)d_in[1];
  const float* v    = (const float*)d_in[2];
  const float* Wq_w = (const float*)d_in[3];
  const float* Wq_b = (const float*)d_in[4];
  const float* Wk_w = (const float*)d_in[5];
  const float* Wk_b = (const float*)d_in[6];
  const float* Wv_w = (const float*)d_in[7];
  const float* Wv_b = (const float*)d_in[8];
  const float* Wo_w = (const float*)d_in[9];
  const float* Wo_b = (const float*)d_in[10];
  const float* pe   = (const float*)d_in[11];
  float* out = (float*)d_out;

  char* W = (char*)d_ws;
  const size_t MB = (size_t)1 << 20;
  us* Qc  = (us*)(W);            // q bf16; dead after QKV gemm -> Obf aliases
  us* Kc  = (us*)(W + 8 * MB);
  us* Vc  = (us*)(W + 16 * MB);
  us* Wqb = (us*)(W + 24 * MB);
  us* Wkb = (us*)(W + 26 * MB);
  us* Wvb = (us*)(W + 28 * MB);
  us* Wob = (us*)(W + 30 * MB);
  us* peT = (us*)(W + 32 * MB);
  us* Qbf = (us*)(W + 33 * MB);
  us* Kbf = (us*)(W + 41 * MB);
  us* VTb = (us*)(W + 49 * MB);
  us* Obf = Qc;                  // reuse after QKV gemm

  castf2b<<<4096, 256, 0, stream>>>(q, Qc, 4194304);
  castf2b<<<4096, 256, 0, stream>>>(k, Kc, 4194304);
  castf2b<<<4096, 256, 0, stream>>>(v, Vc, 4194304);
  castf2b<<<1024, 256, 0, stream>>>(Wq_w, Wqb, 1048576);
  castf2b<<<1024, 256, 0, stream>>>(Wk_w, Wkb, 1048576);
  castf2b<<<1024, 256, 0, stream>>>(Wv_w, Wvb, 1048576);
  castf2b<<<1024, 256, 0, stream>>>(Wo_w, Wob, 1048576);
  transpose_pe<<<1, 256, 0, stream>>>(pe, peT);

  gemm_glds<true><<<dim3(256, 3), 256, 0, stream>>>(
      Qc, Kc, Vc, Wqb, Wkb, Wvb, Wq_b, Wk_b, Wv_b, Qbf, Kbf, Qbf, VTb);
  cope_attn_v15<<<4096, 256, 0, stream>>>(Qbf, Kbf, VTb, peT, Obf);
  gemm_glds<false><<<dim3(256, 1), 256, 0, stream>>>(
      Obf, Obf, Obf, Wob, Wob, Wob, Wo_b, Wo_b, Wo_b, out, out, out, nullptr);
}

// Round 19
// 214.602 us; speedup vs baseline: 1.0355x; 1.0355x over previous
//
#include <hip/hip_runtime.h>
#include <hip/hip_bf16.h>

typedef __attribute__((ext_vector_type(8))) short short8;
typedef __attribute__((ext_vector_type(4))) float f32x4;
typedef unsigned short us;

#define MFMA16(a,b,c) __builtin_amdgcn_mfma_f32_16x16x32_bf16((a),(b),(c),0,0,0)
#define LOG2E 1.4426950408889634f

static __device__ __forceinline__ us bf16r(float x){
  unsigned u = __builtin_bit_cast(unsigned, x);
  u = u + 0x7fffu + ((u >> 16) & 1u);
  return (us)(u >> 16);
}
static __device__ __forceinline__ unsigned cvtpk(float a, float b){
  unsigned r; asm("v_cvt_pk_bf16_f32 %0, %1, %2" : "=v"(r) : "v"(a), "v"(b)); return r;
}
static __device__ __forceinline__ short8 cvt8(float4 a, float4 b){
  uint4 u; u.x = cvtpk(a.x, a.y); u.y = cvtpk(a.z, a.w);
  u.z = cvtpk(b.x, b.y); u.w = cvtpk(b.z, b.w);
  return __builtin_bit_cast(short8, u);
}
static __device__ __forceinline__ float b2f(us h){
  return __builtin_bit_cast(float, (unsigned)h << 16);
}
static __device__ __forceinline__ float PKLO(unsigned u){
  return __builtin_bit_cast(float, u << 16);
}
static __device__ __forceinline__ float PKHI(unsigned u){
  return __builtin_bit_cast(float, u & 0xffff0000u);
}
static __device__ __forceinline__ float exp2fast(float x){
  float r; asm("v_exp_f32 %0, %1" : "=v"(r) : "v"(x)); return r;
}
static __device__ __forceinline__ float rcpfast(float x){
  float r; asm("v_rcp_f32 %0, %1" : "=v"(r) : "v"(x)); return r;
}
static __device__ __forceinline__ float fractfast(float x){
  float r; asm("v_fract_f32 %0, %1" : "=v"(r) : "v"(x)); return r;
}
template<int CTRL, int RMASK>
static __device__ __forceinline__ float dpp_add(float x){
  int t = __builtin_amdgcn_update_dpp(0, __builtin_bit_cast(int, x), CTRL, RMASK, 0xf, false);
  return x + __builtin_bit_cast(float, t);
}
static __device__ __forceinline__ float wave_iscan(float x){
  x = dpp_add<0x111, 0xf>(x);
  x = dpp_add<0x112, 0xf>(x);
  x = dpp_add<0x114, 0xf>(x);
  x = dpp_add<0x118, 0xf>(x);
  x = dpp_add<0x142, 0xa>(x);
  x = dpp_add<0x143, 0xc>(x);
  return x;
}
static __device__ __forceinline__ float lane63(float x){
  return __builtin_bit_cast(float, __builtin_amdgcn_readlane(__builtin_bit_cast(int, x), 63));
}

// ---------------- pos_emb [64d][64n] fp32 -> peT [64n][64d] bf16, pre-scaled by log2(e) ----
__global__ __launch_bounds__(256)
void transpose_pe(const float* __restrict__ pe, us* __restrict__ peT){
  const int t = threadIdx.x;
  const int n = t & 63, dq = t >> 6;
#pragma unroll
  for (int j = 0; j < 16; ++j){
    const int d = dq * 16 + j;
    peT[n * 64 + d] = bf16r(pe[d * 64 + n] * LOG2E);
  }
}

// ---------------- GEMM: C[4096][1024] = A[4096][1024] @ W[1024][1024]^T + bias ----------
// In-register fp32->bf16 cvt on loads (no pre-cast pass). XCD-locality grid swizzle:
// XCD x owns bm in [4x,4x+4) x all bn -> A slice 2MB L2-resident; W streams once/XCD.
// VTo != nullptr && sel==2: write V transposed [b][h][64d][1024s] (fused transpose_v).
template<bool A_BF16, bool OUT_BF16>
__global__ __launch_bounds__(256)
void gemm3(const void* __restrict__ Av0, const void* __restrict__ Av1, const void* __restrict__ Av2,
           const float* __restrict__ W0, const float* __restrict__ W1, const float* __restrict__ W2,
           const float* __restrict__ bp0, const float* __restrict__ bp1, const float* __restrict__ bp2,
           void* __restrict__ O0, void* __restrict__ O1, void* __restrict__ O2,
           us* __restrict__ VTo){
  __shared__ __align__(16) us Al[128 * 64];
  __shared__ __align__(16) us Bl[128 * 64];
  const int sel = blockIdx.y;
  const void* Av   = sel == 0 ? Av0 : (sel == 1 ? Av1 : Av2);
  const float* Wm  = sel == 0 ? W0  : (sel == 1 ? W1  : W2);
  const float* bias = sel == 0 ? bp0 : (sel == 1 ? bp1 : bp2);
  void* Ov         = sel == 0 ? O0  : (sel == 1 ? O1  : O2);
  const int tid = threadIdx.x;
  const int wgs = ((blockIdx.x & 7) << 5) | (blockIdx.x >> 3);   // XCD swizzle (256=8*32)
  const int bm = wgs >> 3, bn = wgs & 7;
  const int m0 = bm << 7, n0 = bn << 7;
  const int w = tid >> 6, l = tid & 63;
  const int lr = l & 15, lg = l >> 4;
  const int wm = (w & 1) << 6, wn = (w >> 1) << 6;
  int srow[4], scol[4], sdst[4];
#pragma unroll
  for (int c = 0; c < 4; ++c){
    const int idx = tid + (c << 8);
    const int r = idx >> 3, cw = idx & 7;
    srow[c] = r; scol[c] = cw << 3;
    sdst[c] = r * 64 + ((cw << 3) ^ ((r & 7) << 3));
  }
  const int swz = (lr & 7) << 3;
  f32x4 acc[4][4];
#pragma unroll
  for (int i = 0; i < 4; ++i)
#pragma unroll
    for (int j = 0; j < 4; ++j) acc[i][j] = (f32x4){0.f, 0.f, 0.f, 0.f};

  auto ldA = [&](int c, int k) -> short8 {
    if constexpr (A_BF16){
      return *(const short8*)((const us*)Av + (size_t)(m0 + srow[c]) * 1024 + k + scol[c]);
    } else {
      const float* p = (const float*)Av + (size_t)(m0 + srow[c]) * 1024 + k + scol[c];
      return cvt8(*(const float4*)p, *(const float4*)(p + 4));
    }
  };
  auto ldW = [&](int c, int k) -> short8 {
    const float* p = Wm + (size_t)(n0 + srow[c]) * 1024 + k + scol[c];
    return cvt8(*(const float4*)p, *(const float4*)(p + 4));
  };

  short8 av[4], bv[4];
#pragma unroll
  for (int c = 0; c < 4; ++c){ av[c] = ldA(c, 0); bv[c] = ldW(c, 0); }

  for (int k0 = 0; k0 < 1024; k0 += 64){
    __syncthreads();
#pragma unroll
    for (int c = 0; c < 4; ++c){
      *(short8*)&Al[sdst[c]] = av[c];
      *(short8*)&Bl[sdst[c]] = bv[c];
    }
    __syncthreads();
    if (k0 < 960){
#pragma unroll
      for (int c = 0; c < 4; ++c){ av[c] = ldA(c, k0 + 64); bv[c] = ldW(c, k0 + 64); }
    }
#pragma unroll
    for (int ks = 0; ks < 2; ++ks){
      short8 af[4], bfv[4];
#pragma unroll
      for (int mt = 0; mt < 4; ++mt)
        af[mt] = *(const short8*)&Al[(wm + mt * 16 + lr) * 64 + (((ks << 5) + (lg << 3)) ^ swz)];
#pragma unroll
      for (int nt = 0; nt < 4; ++nt)
        bfv[nt] = *(const short8*)&Bl[(wn + nt * 16 + lr) * 64 + (((ks << 5) + (lg << 3)) ^ swz)];
#pragma unroll
      for (int mt = 0; mt < 4; ++mt)
#pragma unroll
        for (int nt = 0; nt < 4; ++nt)
          acc[mt][nt] = MFMA16(af[mt], bfv[nt], acc[mt][nt]);
    }
  }
  float bb[4];
#pragma unroll
  for (int nt = 0; nt < 4; ++nt) bb[nt] = bias[n0 + wn + nt * 16 + lr];
  if (VTo != nullptr && sel == 2){
    // fused V-transpose epilogue: 4 consecutive s per acc tile -> one uint2 store
#pragma unroll
    for (int mt = 0; mt < 4; ++mt)
#pragma unroll
      for (int nt = 0; nt < 4; ++nt){
        const int n = n0 + wn + nt * 16 + lr;
        const int hh = n >> 6, dd = n & 63;
        const int mS = m0 + wm + mt * 16 + lg * 4;
        const int bb2 = mS >> 10, ss = mS & 1023;
        uint2 pk;
        pk.x = cvtpk(acc[mt][nt][0] + bb[nt], acc[mt][nt][1] + bb[nt]);
        pk.y = cvtpk(acc[mt][nt][2] + bb[nt], acc[mt][nt][3] + bb[nt]);
        *(uint2*)&VTo[((size_t)((bb2 * 16 + hh) * 64 + dd)) * 1024 + ss] = pk;
      }
    return;
  }
#pragma unroll
  for (int mt = 0; mt < 4; ++mt)
#pragma unroll
    for (int nt = 0; nt < 4; ++nt)
#pragma unroll
      for (int r = 0; r < 4; ++r){
        const size_t m = m0 + wm + mt * 16 + lg * 4 + r;
        const size_t n = n0 + wn + nt * 16 + lr;
        const float vv = acc[mt][nt][r] + bb[nt];
        if (OUT_BF16) ((us*)Ov)[m * 1024 + n] = bf16r(vv);
        else          ((float*)Ov)[m * 1024 + n] = vv;
      }
}

// ---------------- fused CoPE attention v15 (best known: ~136 us) ------
__global__ __launch_bounds__(256, 4)
void cope_attn_v15(const us* __restrict__ Qb, const us* __restrict__ Kb,
                   const us* __restrict__ VT, const us* __restrict__ peT,
                   us* __restrict__ Ob){
  __shared__ __align__(16) unsigned uls[8 * 512];   // 16 KB transit/P union
  __shared__ float sums[16];
  us* yl16 = (us*)uls;
  char* ybytes = (char*)uls;
  const int tid = threadIdx.x;
  const int w = tid >> 6, l = tid & 63;
  const int lr = l & 15, lg = l >> 4;
  const int wg = ((blockIdx.x & 7) << 9) | (blockIdx.x >> 3);  // XCD swizzle
  const int qt = wg & 63;
  const int bh = wg >> 6;
  const int b = bh >> 4, h = bh & 15;
  const int q0 = qt << 4;
  const us* Qh = Qb + ((size_t)(b * 1024 + q0)) * 1024 + h * 64;
  const us* Kh = Kb + ((size_t)(b * 1024)) * 1024 + h * 64;
  const us* Vh = VT + ((size_t)bh) * 64 * 1024;
  const float QSC = 0.125f * LOG2E;
  const f32x4 zf = (f32x4){0.f, 0.f, 0.f, 0.f};

  const short8 aq0 = *(const short8*)(Qh + (size_t)lr * 1024 + lg * 8);
  const short8 aq1 = *(const short8*)(Qh + (size_t)lr * 1024 + 32 + lg * 8);

  // 1) li[q][n] = (Q . pos_emb)*log2e
  {
    f32x4 a = zf;
    const short8 p0 = *(const short8*)(peT + (size_t)(w * 16 + lr) * 64 + lg * 8);
    const short8 p1 = *(const short8*)(peT + (size_t)(w * 16 + lr) * 64 + 32 + lg * 8);
    a = MFMA16(aq0, p0, a);
    a = MFMA16(aq1, p1, a);
#pragma unroll
    for (int r = 0; r < 4; ++r) yl16[(lg * 4 + r) * 64 + w * 16 + lr] = bf16r(a[r]);
  }
  __syncthreads();
  // 2) per-row register tables: lane n holds {li[n], li[n+1]-li[n]}
  unsigned trow[4];
#pragma unroll
  for (int rr = 0; rr < 4; ++rr){
    const int row = w * 4 + rr;
    const us lov = yl16[row * 64 + l];
    const us hiv = (l < 63) ? yl16[row * 64 + l + 1] : lov;
    const float dif = b2f(hiv) - b2f(lov);
    trow[rr] = (unsigned)lov | ((unsigned)bf16r(dif) << 16);
  }

  float carry[4] = {0.f, 0.f, 0.f, 0.f};
  f32x4 oacc = (f32x4){0.f, 0.f, 0.f, 0.f};
  const int d0 = w * 16;
  const int psw = lr & 7;

  for (int c = 1; c >= 0; --c){
    const int koff = c << 9;
    __syncthreads();
    // 3) QK^T -> packed u32 transit [pair][k]; wave keys [128w,128w+128)
    {
      const int kbase = w << 7;
      const us* Kw = Kh + (size_t)(koff + kbase + lr) * 1024 + lg * 8;
      for (int t = 0; t < 8; ++t){
        const short8 b0 = *(const short8*)(Kw + (size_t)(t * 16) * 1024);
        const short8 b1 = *(const short8*)(Kw + (size_t)(t * 16) * 1024 + 32);
        f32x4 a = zf;
        a = MFMA16(aq0, b0, a);
        a = MFMA16(aq1, b1, a);
        const int kc = kbase + t * 16 + lr;
        uls[(lg * 2) * 512 + kc]     = cvtpk(a[0] * QSC, a[1] * QSC);
        uls[(lg * 2 + 1) * 512 + kc] = cvtpk(a[2] * QSC, a[3] * QSC);
      }
    }
    __syncthreads();
    // 4) CoPE: wave owns pairs {2w,2w+1} = q rows 4w..4w+3; lane owns k [8l,8l+8)
#pragma unroll
    for (int pp = 0; pp < 2; ++pp){
      const int pr = w * 2 + pp;
      const uint4 ra = *(const uint4*)&uls[pr * 512 + l * 8];
      const uint4 rb = *(const uint4*)&uls[pr * 512 + l * 8 + 4];
#pragma unroll
      for (int par = 0; par < 2; ++par){
        const int rr = pp * 2 + par;
        const int row = w * 4 + rr;
        float x[8];
        if (par == 0){
          x[0] = PKLO(ra.x); x[1] = PKLO(ra.y); x[2] = PKLO(ra.z); x[3] = PKLO(ra.w);
          x[4] = PKLO(rb.x); x[5] = PKLO(rb.y); x[6] = PKLO(rb.z); x[7] = PKLO(rb.w);
        } else {
          x[0] = PKHI(ra.x); x[1] = PKHI(ra.y); x[2] = PKHI(ra.z); x[3] = PKHI(ra.w);
          x[4] = PKHI(rb.x); x[5] = PKHI(rb.y); x[6] = PKHI(rb.z); x[7] = PKHI(rb.w);
        }
        float sum = 0.f;
        if (c == 0 && carry[rr] >= 63.f){
          const float li63 = b2f((us)(unsigned)__builtin_amdgcn_readlane((int)trow[rr], 63));
#pragma unroll
          for (int i = 0; i < 8; ++i){
            const float e = exp2fast(x[i] + li63);
            x[i] = e;
            sum += e;
          }
        } else {
          float g[8];
#pragma unroll
          for (int i = 0; i < 8; ++i) g[i] = rcpfast(1.f + exp2fast(-x[i]));
          const float a1 = g[0] + g[1];
          const float a3 = g[2] + g[3];
          const float a5 = g[4] + g[5];
          const float a7 = g[6] + g[7];
          const float b2v = g[2] + a1;
          const float b3v = a3 + a1;
          const float i4 = g[4] + b3v;
          const float i5 = a5 + b3v;
          const float i6 = g[6] + a5 + b3v;
          const float s  = a7 + a5 + b3v;
          float pref[8];
          pref[0] = 0.f;  pref[1] = g[0]; pref[2] = a1;  pref[3] = b2v;
          pref[4] = b3v;  pref[5] = i4;   pref[6] = i5;  pref[7] = i6;
          const float run = wave_iscan(s);
          const float T = lane63(run);
          const float base = carry[rr] + T - (run - s);
          carry[rr] += T;
          const unsigned tbl = trow[rr];
#pragma unroll
          for (int i = 0; i < 8; ++i){
            float p = base - pref[i];
            p = __builtin_amdgcn_fmed3f(p, 0.f, 63.f);
            const int il = (int)p;
            const float wt = fractfast(p);
            const unsigned pr2 = (unsigned)__builtin_amdgcn_ds_bpermute(il << 2, (int)tbl);
            const float lo  = __builtin_bit_cast(float, pr2 << 16);
            const float dif = __builtin_bit_cast(float, pr2 & 0xffff0000u);
            const float e = exp2fast(x[i] + lo + wt * dif);
            x[i] = e;
            sum += e;
          }
        }
        const float rs = lane63(wave_iscan(sum));
        if (l == 0){
          if (c == 1) sums[row] = rs;
          else        sums[row] += rs;
        }
        uint4 ua;
        ua.x = cvtpk(x[0], x[1]); ua.y = cvtpk(x[2], x[3]);
        ua.z = cvtpk(x[4], x[5]); ua.w = cvtpk(x[6], x[7]);
        *(uint4*)(ybytes + row * 1024 + ((l ^ (row & 7)) << 4)) = ua;
      }
    }
    __syncthreads();
    // 5) PV accumulate: wave w owns d-tile [16w,16w+16)
    {
      const us* Vw = Vh + (size_t)(d0 + lr) * 1024 + koff + lg * 8;
      for (int ks = 0; ks < 16; ++ks){
        const short8 vb = *(const short8*)(Vw + ks * 32);
        const short8 pa = *(const short8*)(ybytes + lr * 1024 + ((((ks << 2) + lg) ^ psw) << 4));
        oacc = MFMA16(pa, vb, oacc);
      }
    }
  }
  __syncthreads();
#pragma unroll
  for (int r = 0; r < 4; ++r){
    const float inv = rcpfast(sums[lg * 4 + r]);
    Ob[((size_t)(b * 1024 + q0 + lg * 4 + r)) * 1024 + h * 64 + d0 + lr] = bf16r(oacc[r] * inv);
  }
}

extern "C" void kernel_launch(void* const* d_in, const int* in_sizes, int n_in,
                              void* d_out, int out_size, void* d_ws, size_t ws_size,
                              hipStream_t stream) {
  const float* q    = (const float*)d_in[0];
  const float* k    = (const float*)d_in[1];
  const float* v    = (const float*)d_in[2];
  const float* Wq_w = (const float*)d_in[3];
  const float* Wq_b = (const float*)d_in[4];
  const float* Wk_w = (const float*)d_in[5];
  const float* Wk_b = (const float*)d_in[6];
  const float* Wv_w = (const float*)d_in[7];
  const float* Wv_b = (const float*)d_in[8];
  const float* Wo_w = (const float*)d_in[9];
  const float* Wo_b = (const float*)d_in[10];
  const float* pe   = (const float*)d_in[11];
  float* out = (float*)d_out;

  char* W = (char*)d_ws;
  const size_t MB = (size_t)1 << 20;
  us* Qbf = (us*)(W);
  us* Kbf = (us*)(W + 8 * MB);
  us* VTb = (us*)(W + 16 * MB);
  us* Obf = (us*)(W + 24 * MB);
  us* peT = (us*)(W + 32 * MB);

  transpose_pe<<<1, 256, 0, stream>>>(pe, peT);
  gemm3<false, true><<<dim3(256, 3), 256, 0, stream>>>(
      q, k, v, Wq_w, Wk_w, Wv_w, Wq_b, Wk_b, Wv_b, Qbf, Kbf, Qbf, VTb);
  cope_attn_v15<<<4096, 256, 0, stream>>>(Qbf, Kbf, VTb, peT, Obf);
  gemm3<true, false><<<dim3(256, 1), 256, 0, stream>>>(
      Obf, Obf, Obf, Wo_w, Wo_w, Wo_w, Wo_b, Wo_b, Wo_b, out, out, out, nullptr);
}